// Round 8
// baseline (139.909 us; speedup 1.0000x reference)
//
#include <hip/hip_runtime.h>
#include <float.h>

#define K_CODES 1024
#define DIM 64
#define T_LEN 8192
#define N_TOK 131072          // 16 * 8192 tokens
#define LO_SCALE 2048.0f
#define LO_INV   (1.0f / 2048.0f)

typedef _Float16 half8 __attribute__((ext_vector_type(8)));  // 4 VGPRs: MFMA A/B frag
typedef float    f32x4 __attribute__((ext_vector_type(4)));  // MFMA C/D frag

#define MFMA16(a, b, c) __builtin_amdgcn_mfma_f32_16x16x32_f16((a), (b), (c), 0, 0, 0)

typedef __attribute__((address_space(3))) void* as3_void;
typedef const __attribute__((address_space(1))) void* as1_cvoid;

// async global->LDS, 16B per lane; LDS dest = wave-uniform base + lane*16.
__device__ inline void async_16B(const void* g, void* l) {
#if __has_builtin(__builtin_amdgcn_global_load_lds)
    __builtin_amdgcn_global_load_lds((as1_cvoid)g, (as3_void)l, 16, 0, 0);
#else
    *(float4*)l = *(const float4*)g;   // fallback: VGPR round-trip
#endif
}

// ---------------- prep: codebook -> tiled f16 hi/lo + e_sq (unchanged r6/r7) ----------------
// Tile ct (16 codes) = 4 KB contiguous, frag order: hi[q=0..7][code=0..15][j=0..7], lo at +1024.
__global__ void vq_prep(const float* __restrict__ cb,
                        _Float16* __restrict__ w,
                        float* __restrict__ wesq) {
    __shared__ float part[128];
    const int ct   = blockIdx.x;
    const int r    = threadIdx.x;
    const int halF = r >> 7;           // 0: hi chunk, 1: lo chunk
    const int rr   = r & 127;
    const int q    = rr >> 4;          // k-octet
    const int code = rr & 15;

    const float* src = cb + (size_t)(ct * 16 + code) * DIM + q * 8;
    float4 v0 = *reinterpret_cast<const float4*>(src);
    float4 v1 = *reinterpret_cast<const float4*>(src + 4);
    float x[8] = {v0.x, v0.y, v0.z, v0.w, v1.x, v1.y, v1.z, v1.w};

    half8 o;
    float psum = 0.0f;
    #pragma unroll
    for (int j = 0; j < 8; ++j) {
        _Float16 h = (_Float16)x[j];
        o[j] = halF ? (_Float16)((x[j] - (float)h) * LO_SCALE) : h;  // (x-h) exact in fp32
        psum = fmaf(x[j], x[j], psum);
    }
    *reinterpret_cast<half8*>(w + (size_t)ct * 2048 + halF * 1024 + q * 128 + code * 8) = o;

    if (halF == 0) part[rr] = psum;
    __syncthreads();
    if (r < 16) {
        float s = 0.0f;
        #pragma unroll
        for (int q2 = 0; q2 < 8; ++q2) s += part[q2 * 16 + r];
        wesq[ct * 16 + r] = s;
    }
}

// ---------------- main: high-TLP LDS-staged split-f16 MFMA + fused argmin ----------------
// r6 (global B) and r7 (LDS B) both plateau ~65-72us with identical MFMA busy time
// -> B delivery is NOT the bottleneck; 16 waves/CU (grid-capped) is. This round:
// 16 tokens/wave, 64-token blocks, grid 2048, LDS 20.3 KB, launch_bounds(256,6)
// -> 24-28 waves/CU (1.75x TLP), halved per-wave serial segments.
__global__ __launch_bounds__(256, 6)
void vq_main(const float* __restrict__ in,
             const float* __restrict__ cb,
             const _Float16* __restrict__ w,
             const float* __restrict__ wesq,
             float* __restrict__ out) {
    __shared__ __align__(16) _Float16 bt[2][2][2048];  // 2 bufs x 2 tiles x 4 KB = 16 KB
    __shared__ float esq_s[K_CODES];                   // 4 KB
    __shared__ int   idx_s[64];

    const int tid  = threadIdx.x;
    const int wave = tid >> 6;
    const int lane = tid & 63;
    const int lo4  = lane & 15;   // code residue (C col) / token residue (A m)
    const int quad = lane >> 4;   // k-octet selector in A/B frags; token-row group in C

    for (int k = tid; k < K_CODES; k += 256) esq_s[k] = wesq[k];

    const int strip = blockIdx.x * 64 + wave * 16;   // 16 tokens per wave
    const int b  = strip >> 13;
    const int t0 = strip & 8191;

    // ---- A fragments: -2 * X[token][d] -> f16 hi/lo (layout HW-verified r2-r7) ----
    const float* xin = in + (size_t)b * DIM * T_LEN + t0;
    half8 a_hi[2], a_lo[2];
    #pragma unroll
    for (int s = 0; s < 2; ++s) {
        half8 hh, ll;
        #pragma unroll
        for (int j = 0; j < 8; ++j) {
            const int d = s * 32 + quad * 8 + j;
            float xv = -2.0f * xin[(size_t)d * T_LEN + lo4];
            _Float16 h = (_Float16)xv;
            hh[j] = h;
            ll[j] = (_Float16)((xv - (float)h) * LO_SCALE);
        }
        a_hi[s] = hh;
        a_lo[s] = ll;
    }

    float best[4];
    int   bidx[4];
    #pragma unroll
    for (int i = 0; i < 4; ++i) { best[i] = FLT_MAX; bidx[i] = 0; }

    // stage period `per` (tiles 2per, 2per+1 = 8 KB) into bt[buf]:
    // 8 chunks of 1 KB; wave W issues chunks {W, W+4} (chunk index wave-uniform).
    const char* wbytes = (const char*)w;
    auto stage = [&](int per, int buf) {
        const char* src = wbytes + (size_t)per * 8192 + lane * 16;
        char* dst = (char*)&bt[buf][0][0] + lane * 16;
        #pragma unroll
        for (int i = 0; i < 2; ++i) {
            const int c = (wave + i * 4) * 1024;
            async_16B(src + c, dst + c);
        }
    };

    stage(0, 0);
    __syncthreads();   // drains vmcnt: buf 0 + esq_s ready

    for (int per = 0; per < 32; ++per) {
        const int buf = per & 1;
        if (per < 31) stage(per + 1, buf ^ 1);   // in flight during this period's compute
        #pragma unroll
        for (int j = 0; j < 2; ++j) {
            const int ct = per * 2 + j;
            const _Float16* tp = &bt[buf][j][lane * 8];
            half8 h0 = *reinterpret_cast<const half8*>(tp);          // hi, k 0..31
            half8 h1 = *reinterpret_cast<const half8*>(tp + 512);    // hi, k 32..63
            half8 l0 = *reinterpret_cast<const half8*>(tp + 1024);   // lo, k 0..31
            half8 l1 = *reinterpret_cast<const half8*>(tp + 1536);   // lo, k 32..63
            const float es = esq_s[ct * 16 + lo4];
            const int code = ct * 16 + lo4;
            f32x4 c1 = {es, es, es, es};    // ||e||^2 folded into C input
            f32x4 c2 = {0.f, 0.f, 0.f, 0.f};
            c1 = MFMA16(a_hi[0], h0, c1);
            c1 = MFMA16(a_hi[1], h1, c1);
            c2 = MFMA16(a_lo[0], h0, c2);
            c2 = MFMA16(a_lo[1], h1, c2);
            c2 = MFMA16(a_hi[0], l0, c2);
            c2 = MFMA16(a_hi[1], l1, c2);
            #pragma unroll
            for (int r = 0; r < 4; ++r) {
                float sc = fmaf(c2[r], LO_INV, c1[r]);  // ||e||^2 - 2 x.e
                bool lt = sc < best[r];                  // strict <: first occurrence wins
                best[r] = lt ? sc : best[r];
                bidx[r] = lt ? code : bidx[r];
            }
        }
        __syncthreads();   // all waves done with buf; next buf's loads drained
    }

    // ---- cross-lane merge over the 16 code-residue lanes ----
    #pragma unroll
    for (int i = 0; i < 4; ++i) {
        float s = best[i];
        int  ix = bidx[i];
        #pragma unroll
        for (int off = 1; off < 16; off <<= 1) {
            float s2 = __shfl_xor(s, off, 64);
            int  ix2 = __shfl_xor(ix, off, 64);
            bool take = (s2 < s) || (s2 == s && ix2 < ix);  // tie -> lower index
            s  = take ? s2 : s;
            ix = take ? ix2 : ix;
        }
        if (lo4 == 0) {
            // token_local = quad*4 + i
            idx_s[wave * 16 + quad * 4 + i] = ix;
        }
    }
    __syncthreads();

    // ---- epilogue: 4 threads per token (16 dims each), gather + coalesced store ----
    const int tok_local = tid & 63;                // block covers 64 contiguous tokens
    const int part = tid >> 6;                     // dims part*16 .. part*16+15
    const int token = blockIdx.x * 64 + tok_local;
    const int tb = token >> 13;
    const int tt = token & 8191;
    const int my_idx = idx_s[tok_local];

    if (part == 0)
        out[(size_t)N_TOK * DIM + token] = (float)my_idx;   // index output

    const float* crow = cb + (size_t)my_idx * DIM + part * 16;
    float* outv = out + (size_t)tb * DIM * T_LEN + (size_t)(part * 16) * T_LEN + tt;
    #pragma unroll
    for (int d0 = 0; d0 < 16; d0 += 4) {
        float4 v = *reinterpret_cast<const float4*>(crow + d0);  // L2-hot gather
        outv[(size_t)(d0 + 0) * T_LEN] = v.x;
        outv[(size_t)(d0 + 1) * T_LEN] = v.y;
        outv[(size_t)(d0 + 2) * T_LEN] = v.z;
        outv[(size_t)(d0 + 3) * T_LEN] = v.w;
    }
}

extern "C" void kernel_launch(void* const* d_in, const int* in_sizes, int n_in,
                              void* d_out, int out_size, void* d_ws, size_t ws_size,
                              hipStream_t stream) {
    const float* in = (const float*)d_in[0];   // (16, 64, 8192) fp32
    const float* cb = (const float*)d_in[1];   // (1024, 64) fp32
    float* out = (float*)d_out;

    _Float16* w   = (_Float16*)d_ws;                       // 64 tiles * 4 KB = 256 KB
    float*   wesq = (float*)((char*)d_ws + 64 * 4096);     // 4 KB

    vq_prep<<<dim3(64), dim3(256), 0, stream>>>(cb, w, wesq);
    vq_main<<<dim3(N_TOK / 64), dim3(256), 0, stream>>>(in, cb, w, wesq, out);
}

// Round 9
// 138.249 us; speedup vs baseline: 1.0120x; 1.0120x over previous
//
#include <hip/hip_runtime.h>
#include <float.h>

#define K_CODES 1024
#define DIM 64
#define T_LEN 8192
#define N_TOK 131072          // 16 * 8192 tokens
#define LO_SCALE 2048.0f
#define LO_INV   (1.0f / 2048.0f)

typedef _Float16 half8 __attribute__((ext_vector_type(8)));  // 4 VGPRs: MFMA A/B frag
typedef float    f32x4 __attribute__((ext_vector_type(4)));  // MFMA C/D frag

#define MFMA16(a, b, c) __builtin_amdgcn_mfma_f32_16x16x32_f16((a), (b), (c), 0, 0, 0)

typedef __attribute__((address_space(3))) void* as3_void;
typedef const __attribute__((address_space(1))) void* as1_cvoid;

__device__ inline void async_16B(const void* g, void* l) {
#if __has_builtin(__builtin_amdgcn_global_load_lds)
    __builtin_amdgcn_global_load_lds((as1_cvoid)g, (as3_void)l, 16, 0, 0);
#else
    *(float4*)l = *(const float4*)g;
#endif
}

// ---------------- prep: codebook -> tiled f16 hi/lo + e_sq (unchanged r6-r8) ----------------
__global__ void vq_prep(const float* __restrict__ cb,
                        _Float16* __restrict__ w,
                        float* __restrict__ wesq) {
    __shared__ float part[128];
    const int ct   = blockIdx.x;
    const int r    = threadIdx.x;
    const int halF = r >> 7;
    const int rr   = r & 127;
    const int q    = rr >> 4;
    const int code = rr & 15;

    const float* src = cb + (size_t)(ct * 16 + code) * DIM + q * 8;
    float4 v0 = *reinterpret_cast<const float4*>(src);
    float4 v1 = *reinterpret_cast<const float4*>(src + 4);
    float x[8] = {v0.x, v0.y, v0.z, v0.w, v1.x, v1.y, v1.z, v1.w};

    half8 o;
    float psum = 0.0f;
    #pragma unroll
    for (int j = 0; j < 8; ++j) {
        _Float16 h = (_Float16)x[j];
        o[j] = halF ? (_Float16)((x[j] - (float)h) * LO_SCALE) : h;
        psum = fmaf(x[j], x[j], psum);
    }
    *reinterpret_cast<half8*>(w + (size_t)ct * 2048 + halF * 1024 + q * 128 + code * 8) = o;

    if (halF == 0) part[rr] = psum;
    __syncthreads();
    if (r < 16) {
        float s = 0.0f;
        #pragma unroll
        for (int q2 = 0; q2 < 8; ++q2) s += part[q2 * 16 + r];
        wesq[ct * 16 + r] = s;
    }
}

// ---------------- main: period-batched MFMA burst + deferred argmin ----------------
// r6/r7/r8 falsified B-path, L2 pressure, and occupancy as bottlenecks (all ~65-72us,
// MFMA busy pinned ~21.5us). This round changes ONLY per-wave ILP structure:
// per 4-tile period: all 20 ds_reads upfront -> 48 back-to-back MFMAs (8 independent
// acc chains, max depth 4) -> one 32-slot argmin burst. MFMA stream/period: ~930 cyc.
__global__ __launch_bounds__(256, 2)
void vq_main(const float* __restrict__ in,
             const float* __restrict__ cb,
             const _Float16* __restrict__ w,
             const float* __restrict__ wesq,
             float* __restrict__ out) {
    __shared__ __align__(16) _Float16 bt[2][4][2048];  // 2 bufs x 4 tiles x 4 KB = 32 KB
    __shared__ float esq_s[K_CODES];                   // 4 KB
    __shared__ int   idx_s[128];

    const int tid  = threadIdx.x;
    const int wave = tid >> 6;
    const int lane = tid & 63;
    const int lo4  = lane & 15;
    const int quad = lane >> 4;

    for (int k = tid; k < K_CODES; k += 256) esq_s[k] = wesq[k];

    const int strip = blockIdx.x * 128 + wave * 32;   // 32 tokens per wave
    const int b  = strip >> 13;
    const int t0 = strip & 8191;

    // ---- A fragments: -2 * X[token][d] -> f16 hi/lo (layout HW-verified r2-r8) ----
    const float* xin = in + (size_t)b * DIM * T_LEN + t0;
    half8 a_hi[2][2], a_lo[2][2];
    #pragma unroll
    for (int mt = 0; mt < 2; ++mt) {
        #pragma unroll
        for (int s = 0; s < 2; ++s) {
            half8 hh, ll;
            #pragma unroll
            for (int j = 0; j < 8; ++j) {
                const int d = s * 32 + quad * 8 + j;
                float xv = -2.0f * xin[(size_t)d * T_LEN + mt * 16 + lo4];
                _Float16 h = (_Float16)xv;
                hh[j] = h;
                ll[j] = (_Float16)((xv - (float)h) * LO_SCALE);
            }
            a_hi[mt][s] = hh;
            a_lo[mt][s] = ll;
        }
    }

    float best[8];
    int   bidx[8];
    #pragma unroll
    for (int i = 0; i < 8; ++i) { best[i] = FLT_MAX; bidx[i] = 0; }

    // stage period `per` (tiles 4per..4per+3, 16 KB): 16 chunks of 1 KB,
    // wave W issues chunks {W, W+4, W+8, W+12}.
    const char* wbytes = (const char*)w;
    auto stage = [&](int per, int buf) {
        const char* src = wbytes + (size_t)per * 16384 + lane * 16;
        char* dst = (char*)&bt[buf][0][0] + lane * 16;
        #pragma unroll
        for (int i = 0; i < 4; ++i) {
            const int c = (wave + i * 4) * 1024;
            async_16B(src + c, dst + c);
        }
    };

    stage(0, 0);
    __syncthreads();

    for (int per = 0; per < 16; ++per) {
        const int buf = per & 1;
        if (per < 15) stage(per + 1, buf ^ 1);   // in flight during this period's compute

        // ---- phase 1: ALL B fragments + esq of this period, independent ds_reads ----
        half8 Bh0[4], Bh1[4], Bl0[4], Bl1[4];
        float Es[4];
        #pragma unroll
        for (int j = 0; j < 4; ++j) {
            const _Float16* tp = &bt[buf][j][lane * 8];
            Bh0[j] = *reinterpret_cast<const half8*>(tp);
            Bh1[j] = *reinterpret_cast<const half8*>(tp + 512);
            Bl0[j] = *reinterpret_cast<const half8*>(tp + 1024);
            Bl1[j] = *reinterpret_cast<const half8*>(tp + 1536);
            Es[j]  = esq_s[(per * 4 + j) * 16 + lo4];
        }

        // ---- phase 2: 48 back-to-back MFMAs, 8 independent (ct,mt) chain groups ----
        f32x4 C1[4][2], C2[4][2];
        #pragma unroll
        for (int j = 0; j < 4; ++j) {
            #pragma unroll
            for (int mt = 0; mt < 2; ++mt) {
                f32x4 c1 = {Es[j], Es[j], Es[j], Es[j]};
                f32x4 c2 = {0.f, 0.f, 0.f, 0.f};
                c1 = MFMA16(a_hi[mt][0], Bh0[j], c1);
                c1 = MFMA16(a_hi[mt][1], Bh1[j], c1);
                c2 = MFMA16(a_lo[mt][0], Bh0[j], c2);
                c2 = MFMA16(a_lo[mt][1], Bh1[j], c2);
                c2 = MFMA16(a_hi[mt][0], Bl0[j], c2);
                c2 = MFMA16(a_hi[mt][1], Bl1[j], c2);
                C1[j][mt] = c1;
                C2[j][mt] = c2;
            }
        }

        // ---- phase 3: one argmin burst over 32 slots ----
        #pragma unroll
        for (int j = 0; j < 4; ++j) {
            const int code = (per * 4 + j) * 16 + lo4;
            #pragma unroll
            for (int mt = 0; mt < 2; ++mt) {
                #pragma unroll
                for (int r = 0; r < 4; ++r) {
                    float sc = fmaf(C2[j][mt][r], LO_INV, C1[j][mt][r]);
                    const int i = mt * 4 + r;
                    bool lt = sc < best[i];          // strict <: first occurrence wins
                    best[i] = lt ? sc : best[i];
                    bidx[i] = lt ? code : bidx[i];
                }
            }
        }
        __syncthreads();
    }

    // ---- cross-lane merge over the 16 code-residue lanes ----
    #pragma unroll
    for (int i = 0; i < 8; ++i) {
        float s = best[i];
        int  ix = bidx[i];
        #pragma unroll
        for (int off = 1; off < 16; off <<= 1) {
            float s2 = __shfl_xor(s, off, 64);
            int  ix2 = __shfl_xor(ix, off, 64);
            bool take = (s2 < s) || (s2 == s && ix2 < ix);  // tie -> lower index
            s  = take ? s2 : s;
            ix = take ? ix2 : ix;
        }
        if (lo4 == 0) {
            idx_s[wave * 32 + (i >> 2) * 16 + quad * 4 + (i & 3)] = ix;
        }
    }
    __syncthreads();

    // ---- epilogue: 2 threads per token (32 dims each), gather + coalesced store ----
    const int tok_local = tid & 127;
    const int dhalf = tid >> 7;
    const int token = blockIdx.x * 128 + tok_local;
    const int tb = token >> 13;
    const int tt = token & 8191;
    const int my_idx = idx_s[tok_local];

    if (dhalf == 0)
        out[(size_t)N_TOK * DIM + token] = (float)my_idx;   // index output

    const float* crow = cb + (size_t)my_idx * DIM + dhalf * 32;
    float* outv = out + (size_t)tb * DIM * T_LEN + (size_t)(dhalf * 32) * T_LEN + tt;
    #pragma unroll
    for (int d0 = 0; d0 < 32; d0 += 4) {
        float4 v = *reinterpret_cast<const float4*>(crow + d0);  // L2-hot gather
        outv[(size_t)(d0 + 0) * T_LEN] = v.x;
        outv[(size_t)(d0 + 1) * T_LEN] = v.y;
        outv[(size_t)(d0 + 2) * T_LEN] = v.z;
        outv[(size_t)(d0 + 3) * T_LEN] = v.w;
    }
}

extern "C" void kernel_launch(void* const* d_in, const int* in_sizes, int n_in,
                              void* d_out, int out_size, void* d_ws, size_t ws_size,
                              hipStream_t stream) {
    const float* in = (const float*)d_in[0];   // (16, 64, 8192) fp32
    const float* cb = (const float*)d_in[1];   // (1024, 64) fp32
    float* out = (float*)d_out;

    _Float16* w   = (_Float16*)d_ws;                       // 64 tiles * 4 KB = 256 KB
    float*   wesq = (float*)((char*)d_ws + 64 * 4096);     // 4 KB

    vq_prep<<<dim3(64), dim3(256), 0, stream>>>(cb, w, wesq);
    vq_main<<<dim3(N_TOK / 128), dim3(256), 0, stream>>>(in, cb, w, wesq, out);
}

// Round 10
// 128.172 us; speedup vs baseline: 1.0916x; 1.0786x over previous
//
#include <hip/hip_runtime.h>
#include <float.h>

#define K_CODES 1024
#define DIM 64
#define T_LEN 8192
#define N_TOK 131072          // 16 * 8192 tokens
#define LO_SCALE 2048.0f

typedef _Float16 half8 __attribute__((ext_vector_type(8)));  // 4 VGPRs: MFMA A/B frag
typedef float    f32x4 __attribute__((ext_vector_type(4)));  // MFMA C/D frag

#define MFMA16(a, b, c) __builtin_amdgcn_mfma_f32_16x16x32_f16((a), (b), (c), 0, 0, 0)

// ---------------- prep: codebook -> tiled f16 hi/lo + 2048*e_sq ----------------
// Tile ct (16 codes) = 4 KB contiguous: hi[q=0..7][code=0..15][j=0..7], lo(x2048) at +1024.
// wesq stores 2048*||e||^2 (exact power-of-2 scale) for the scaled-score argmin.
__global__ void vq_prep(const float* __restrict__ cb,
                        _Float16* __restrict__ w,
                        float* __restrict__ wesq) {
    __shared__ float part[128];
    const int ct   = blockIdx.x;
    const int r    = threadIdx.x;
    const int halF = r >> 7;
    const int rr   = r & 127;
    const int q    = rr >> 4;
    const int code = rr & 15;

    const float* src = cb + (size_t)(ct * 16 + code) * DIM + q * 8;
    float4 v0 = *reinterpret_cast<const float4*>(src);
    float4 v1 = *reinterpret_cast<const float4*>(src + 4);
    float x[8] = {v0.x, v0.y, v0.z, v0.w, v1.x, v1.y, v1.z, v1.w};

    half8 o;
    float psum = 0.0f;
    #pragma unroll
    for (int j = 0; j < 8; ++j) {
        _Float16 h = (_Float16)x[j];
        o[j] = halF ? (_Float16)((x[j] - (float)h) * LO_SCALE) : h;  // (x-h) exact in fp32
        psum = fmaf(x[j], x[j], psum);
    }
    *reinterpret_cast<half8*>(w + (size_t)ct * 2048 + halF * 1024 + q * 128 + code * 8) = o;

    if (halF == 0) part[rr] = psum;
    __syncthreads();
    if (r < 16) {
        float s = 0.0f;
        #pragma unroll
        for (int q2 = 0; q2 < 8; ++q2) s += part[q2 * 16 + r];
        wesq[ct * 16 + r] = s * LO_SCALE;   // pre-scaled: score' = 2048 * score
    }
}

// ---------------- main: global-direct B + single-acc scaled score + 3-op argmin ----------------
// r6-r9 lesson: duration ~= SUM of pipe busy times (no cross-wave overlap achievable
// from source). So shrink the non-MFMA pipes: (1) no LDS staging / no loop barriers
// (ds_read pipe -> 0, r6-style free-drifting waves); (2) 64 tok/wave (B loads amortized
// 2x); (3) scaled single accumulator: score' = 2048*||e||^2 + (2048 ah)bh + ah(2048 bl)
// + (2048 al)bh -> no per-slot fmaf, argmin = cmp + 2 cndmask. Same exact f16 product
// set as r2-r9 (x2^11 exact) -> identical argmins.
__global__ __launch_bounds__(256, 2)
void vq_main(const float* __restrict__ in,
             const float* __restrict__ cb,
             const _Float16* __restrict__ w,
             const float* __restrict__ wesq,
             float* __restrict__ out) {
    __shared__ float esq_s[K_CODES];   // 4 KB (scaled x2048)
    __shared__ int   idx_s[256];

    const int tid  = threadIdx.x;
    const int wave = tid >> 6;
    const int lane = tid & 63;
    const int lo4  = lane & 15;   // code residue (C col) / token residue (A m)
    const int quad = lane >> 4;   // k-octet selector; token-row group in C

    for (int k = tid; k < K_CODES; k += 256) esq_s[k] = wesq[k];
    __syncthreads();   // only barrier before the epilogue

    const int strip = blockIdx.x * 256 + wave * 64;   // 64 tokens per wave
    const int b  = strip >> 13;
    const int t0 = strip & 8191;

    // ---- A fragments: -2x -> ah (f16), ah_s = ah*2048 (exact), al = (x-ah)*2048 ----
    const float* xin = in + (size_t)b * DIM * T_LEN + t0;
    half8 a_h[4][2], a_hs[4][2], a_l[4][2];
    #pragma unroll
    for (int mt = 0; mt < 4; ++mt) {
        #pragma unroll
        for (int s = 0; s < 2; ++s) {
            half8 hh, hs, ll;
            #pragma unroll
            for (int j = 0; j < 8; ++j) {
                const int d = s * 32 + quad * 8 + j;
                float xv = -2.0f * xin[(size_t)d * T_LEN + mt * 16 + lo4];
                _Float16 h = (_Float16)xv;
                hh[j] = h;
                hs[j] = (_Float16)((float)h * LO_SCALE);            // exact exponent shift
                ll[j] = (_Float16)((xv - (float)h) * LO_SCALE);
            }
            a_h[mt][s] = hh;
            a_hs[mt][s] = hs;
            a_l[mt][s] = ll;
        }
    }

    float best[16];
    int   bidx[16];
    #pragma unroll
    for (int i = 0; i < 16; ++i) { best[i] = FLT_MAX; bidx[i] = 0; }

    // B frags (layout HW-verified r6): tile base + lane*8, frags at +0/+512/+1024/+1536
    const _Float16* wb = w + (size_t)lane * 8;

    half8 Ah0, Ah1, Al0, Al1, Bh0, Bh1, Bl0, Bl1;
    float Ae, Be;
    auto loadB = [&](int ct, half8& h0, half8& h1, half8& l0, half8& l1, float& es) {
        const _Float16* p = wb + (size_t)ct * 2048;
        h0 = *reinterpret_cast<const half8*>(p);          // hi, k 0..31
        h1 = *reinterpret_cast<const half8*>(p + 512);    // hi, k 32..63
        l0 = *reinterpret_cast<const half8*>(p + 1024);   // lo(x2048), k 0..31
        l1 = *reinterpret_cast<const half8*>(p + 1536);   // lo(x2048), k 32..63
        es = esq_s[ct * 16 + lo4];
    };
    auto step = [&](const half8& h0, const half8& h1, const half8& l0,
                    const half8& l1, float es, int ct) {
        const int code = ct * 16 + lo4;
        #pragma unroll
        for (int mt = 0; mt < 4; ++mt) {
            f32x4 c = {es, es, es, es};        // 2048*||e||^2
            c = MFMA16(a_hs[mt][0], h0, c);    // 2048*ah*bh
            c = MFMA16(a_hs[mt][1], h1, c);
            c = MFMA16(a_h[mt][0], l0, c);     // ah*(2048*bl)
            c = MFMA16(a_h[mt][1], l1, c);
            c = MFMA16(a_l[mt][0], h0, c);     // (2048*al)*bh
            c = MFMA16(a_l[mt][1], h1, c);
            #pragma unroll
            for (int r = 0; r < 4; ++r) {
                float sc = c[r];                // scaled score, no fmaf needed
                const int i = mt * 4 + r;
                bool lt = sc < best[i];         // strict <: first occurrence wins
                best[i] = lt ? sc : best[i];
                bidx[i] = lt ? code : bidx[i];
            }
        }
    };

    // ping-pong: tile ct+1's 4 global loads in flight during tile ct's 24 MFMAs
    loadB(0, Ah0, Ah1, Al0, Al1, Ae);
    loadB(1, Bh0, Bh1, Bl0, Bl1, Be);
    for (int p = 0; p < 31; ++p) {
        step(Ah0, Ah1, Al0, Al1, Ae, 2 * p);
        loadB(2 * p + 2, Ah0, Ah1, Al0, Al1, Ae);
        step(Bh0, Bh1, Bl0, Bl1, Be, 2 * p + 1);
        loadB(2 * p + 3, Bh0, Bh1, Bl0, Bl1, Be);
    }
    step(Ah0, Ah1, Al0, Al1, Ae, 62);
    step(Bh0, Bh1, Bl0, Bl1, Be, 63);

    // ---- cross-lane merge over the 16 code-residue lanes ----
    #pragma unroll
    for (int i = 0; i < 16; ++i) {
        float s = best[i];
        int  ix = bidx[i];
        #pragma unroll
        for (int off = 1; off < 16; off <<= 1) {
            float s2 = __shfl_xor(s, off, 64);
            int  ix2 = __shfl_xor(ix, off, 64);
            bool take = (s2 < s) || (s2 == s && ix2 < ix);  // tie -> lower index
            s  = take ? s2 : s;
            ix = take ? ix2 : ix;
        }
        if (lo4 == 0) {
            // token_local = mt*16 + quad*4 + r,  mt = i>>2, r = i&3
            idx_s[wave * 64 + (i >> 2) * 16 + quad * 4 + (i & 3)] = ix;
        }
    }
    __syncthreads();

    // ---- epilogue: 1 thread per token, gather exact fp32 row + coalesced stores ----
    const int token = blockIdx.x * 256 + tid;
    const int tb = token >> 13;
    const int tt = token & 8191;
    const int my_idx = idx_s[tid];

    out[(size_t)N_TOK * DIM + token] = (float)my_idx;   // index output

    const float* crow = cb + (size_t)my_idx * DIM;
    float* outv = out + (size_t)tb * DIM * T_LEN + tt;
    #pragma unroll
    for (int d0 = 0; d0 < DIM; d0 += 4) {
        float4 v = *reinterpret_cast<const float4*>(crow + d0);  // L2-hot gather
        outv[(size_t)(d0 + 0) * T_LEN] = v.x;
        outv[(size_t)(d0 + 1) * T_LEN] = v.y;
        outv[(size_t)(d0 + 2) * T_LEN] = v.z;
        outv[(size_t)(d0 + 3) * T_LEN] = v.w;
    }
}

extern "C" void kernel_launch(void* const* d_in, const int* in_sizes, int n_in,
                              void* d_out, int out_size, void* d_ws, size_t ws_size,
                              hipStream_t stream) {
    const float* in = (const float*)d_in[0];   // (16, 64, 8192) fp32
    const float* cb = (const float*)d_in[1];   // (1024, 64) fp32
    float* out = (float*)d_out;

    _Float16* w   = (_Float16*)d_ws;                       // 64 tiles * 4 KB = 256 KB
    float*   wesq = (float*)((char*)d_ws + 64 * 4096);     // 4 KB

    vq_prep<<<dim3(64), dim3(256), 0, stream>>>(cb, w, wesq);
    vq_main<<<dim3(N_TOK / 256), dim3(256), 0, stream>>>(in, cb, w, wesq, out);
}